// Round 2
// baseline (51.353 us; speedup 1.0000x reference)
//
#include <hip/hip_runtime.h>

// CumulativeFlattenedLinear: per-64-timestep-window projection (C=16 -> O=16,
// per-s weight slice, first ND=16 slots zero) + causal cumsum within window + bias.
//
// Structure (v2): 4 timesteps per lane via float4. lane = 16*row + r covers
// s = 4r..4r+3 of window (slab_window + row). One wave = 256 consecutive
// timesteps = 4 windows.
// - x loads:  float4 per lane, 1 KiB per wave-instruction, fully coalesced.
// - weights:  straight from global (48 KiB total, L1/L2 resident). Lane r needs
//   keep-indices 4(r-4)..4(r-4)+3 -> one float4, coalesced across a 16-lane row,
//   broadcast across rows. Lanes r<4 are discard slots: totals zeroed pre-scan.
// - cumsum:   lane-local prefix of 4 + DPP row_shr{1,2,4,8} inclusive scan over
//   16-lane rows (row == window), exclusive-adjust, add bias.
// - stores:   float4 per lane, fully coalesced.
// No LDS, no __syncthreads -> occupancy limited only by VGPRs (~16 waves/CU).

#define CC 16
#define TT 131072
#define OO 16
#define NK 48

__device__ __forceinline__ float row_scan16(float v) {
  // inclusive scan across each 16-lane row (bound_ctrl=1 -> 0 shifted in)
  int t;
  t = __builtin_amdgcn_update_dpp(0, __float_as_int(v), 0x111, 0xf, 0xf, true);
  v += __int_as_float(t);
  t = __builtin_amdgcn_update_dpp(0, __float_as_int(v), 0x112, 0xf, 0xf, true);
  v += __int_as_float(t);
  t = __builtin_amdgcn_update_dpp(0, __float_as_int(v), 0x114, 0xf, 0xf, true);
  v += __int_as_float(t);
  t = __builtin_amdgcn_update_dpp(0, __float_as_int(v), 0x118, 0xf, 0xf, true);
  v += __int_as_float(t);
  return v;
}

__global__ __launch_bounds__(256, 4) void cfl_kernel(
    const float* __restrict__ x, const float* __restrict__ weight,
    const float* __restrict__ bias, float* __restrict__ out) {
  const int tid = threadIdx.x;
  const int lane = tid & 63;
  const int wid = tid >> 6;
  const int r = lane & 15;

  const int n = blockIdx.x * 4 + wid;  // wave-slab id, 0..4095
  const int b = n >> 9;                // 512 slabs per batch row
  const int slab = n & 511;            // 256-timestep slab within T

  // x slab into registers: xv[c] = x[b, c, slab*256 + lane*4 .. +3]
  const float4* xb =
      (const float4*)(x + (size_t)b * CC * TT + (size_t)slab * 256) + lane;
  float4 xv[CC];
#pragma unroll
  for (int c = 0; c < CC; ++c) xv[c] = xb[c * (TT / 4)];

  const bool disc = (r < 4);                 // lanes covering s=0..15 (w==0)
  const int woff = disc ? 0 : 4 * (r - 4);   // float index into 48-keep row

  float* ob = out + (size_t)b * OO * TT + (size_t)slab * 256;

  for (int o = 0; o < OO; ++o) {
    float4 acc = make_float4(0.f, 0.f, 0.f, 0.f);
    const float* wrow = weight + o * (CC * NK) + woff;
#pragma unroll
    for (int c = 0; c < CC; ++c) {
      const float4 wf = *(const float4*)(wrow + c * NK);
      acc.x = fmaf(xv[c].x, wf.x, acc.x);
      acc.y = fmaf(xv[c].y, wf.y, acc.y);
      acc.z = fmaf(xv[c].z, wf.z, acc.z);
      acc.w = fmaf(xv[c].w, wf.w, acc.w);
    }
    // discard slots contribute zero
    if (disc) acc = make_float4(0.f, 0.f, 0.f, 0.f);
    // lane-local inclusive prefix
    const float p0 = acc.x;
    const float p1 = p0 + acc.y;
    const float p2 = p1 + acc.z;
    const float p3 = p2 + acc.w;
    // row-wide inclusive scan of lane totals, then exclusive-adjust
    const float inc = row_scan16(p3);
    const float ex = inc - p3 + bias[o];
    const float4 res = make_float4(p0 + ex, p1 + ex, p2 + ex, p3 + ex);
    ((float4*)(ob + (size_t)o * TT))[lane] = res;
  }
}

extern "C" void kernel_launch(void* const* d_in, const int* in_sizes, int n_in,
                              void* d_out, int out_size, void* d_ws, size_t ws_size,
                              hipStream_t stream) {
  const float* x = (const float*)d_in[0];
  const float* weight = (const float*)d_in[1];
  const float* bias = (const float*)d_in[2];
  float* out = (float*)d_out;

  // 8 b * 512 slabs = 4096 wave-slabs; 4 waves/block -> 1024 blocks.
  cfl_kernel<<<1024, 256, 0, stream>>>(x, weight, bias, out);
}